// Round 2
// baseline (608.631 us; speedup 1.0000x reference)
//
#include <hip/hip_runtime.h>
#include <math.h>

#define DD 256
#define KK 1024
#define TT 4096
#define BB 16
#define NN (BB*TT)            // 65536
#define QSZ (BB*DD*TT)        // 16777216
#define LOSS_POS QSZ
#define IDX_OFF (QSZ+1)
#define PERP_POS (QSZ+1+NN)

// workspace layout (bytes)
#define WS_NE   0                    // K floats        [0, 4096)
#define WS_IDX  4096                 // N ints          [4096, 266240)
#define WS_CNT  (4096 + NN*4)        // K ints          [266240, 270336)
#define WS_LOSS (WS_CNT + KK*4)      // 1 double        [270336, 270344)
#define WS_XN   (WS_LOSS + 8)        // N floats        [270344, 532488)

// ---- numpy-exact pairwise sum of squares over 256 elements ----
// numpy pairwise_sum(n=256): split into two 128-blocks; each block uses 8
// accumulators r[j] striding 8, combined ((r0+r1)+(r2+r3))+((r4+r5)+(r6+r7));
// halves added last. Squares are rounded to fp32 first (flat*flat materialized).
// __fadd_rn/__fmul_rn block FMA contraction.
__device__ __forceinline__ float np_pairwise_sq(const float* __restrict__ p,
                                                const long stride) {
    float tot[2];
    #pragma unroll
    for (int h = 0; h < 2; ++h) {
        const float* q = p + (long)h * 128 * stride;
        float r[8];
        #pragma unroll
        for (int j = 0; j < 8; ++j) {
            const float v = q[(long)j * stride];
            r[j] = __fmul_rn(v, v);
        }
        for (int i = 8; i < 128; i += 8) {
            #pragma unroll
            for (int j = 0; j < 8; ++j) {
                const float v = q[(long)(i + j) * stride];
                r[j] = __fadd_rn(r[j], __fmul_rn(v, v));
            }
        }
        tot[h] = __fadd_rn(__fadd_rn(__fadd_rn(r[0], r[1]), __fadd_rn(r[2], r[3])),
                           __fadd_rn(__fadd_rn(r[4], r[5]), __fadd_rn(r[6], r[7])));
    }
    return __fadd_rn(tot[0], tot[1]);
}

// ---------------- kernel A1: ||e_k||^2 (numpy-pairwise) ----------------
__global__ __launch_bounds__(256) void vq_knorm(const float* __restrict__ emb,
                                                float* __restrict__ ne) {
    const int k = blockIdx.x * 256 + threadIdx.x;   // grid = KK/256
    if (k < KK) ne[k] = np_pairwise_sq(emb + (size_t)k * DD, 1);
}

// ---------------- kernel A2: ||x_n||^2 (numpy-pairwise) ----------------
__global__ __launch_bounds__(256) void vq_xnorm(const float* __restrict__ x,
                                                float* __restrict__ xn) {
    const int n = blockIdx.x * 256 + threadIdx.x;   // grid = NN/256
    const int b = n >> 12;
    const int t = n & 4095;
    xn[n] = np_pairwise_sq(x + (size_t)b * DD * TT + t, TT);
}

// ---------------- kernel B: argmin over K ----------------
// block tile: 128 k x 128 t, thread tile 8x8, d-chunk 32
#define BM 128
#define BN 128
#define BKD 32
#define LDP 132   // padded row stride (words)

__global__ __launch_bounds__(256) void vq_argmin(
    const float* __restrict__ x,    // [B, D, T]
    const float* __restrict__ emb,  // [K, D]
    const float* __restrict__ ne,   // [K]
    const float* __restrict__ xn,   // [N]
    int* __restrict__ out_idx)      // [N]
{
    __shared__ float eT[BKD][LDP];   // [d][k]
    __shared__ float xs[BKD][LDP];   // [d][t]
    __shared__ float nes[KK];
    __shared__ float redv[16][16][8];
    __shared__ int   redi[16][16][8];

    const int tid = threadIdx.x;
    const int bx  = blockIdx.x;        // 512 blocks
    const int b   = bx >> 5;           // / (T/BN = 32)
    const int t0  = (bx & 31) * BN;
    const int ki  = tid >> 4;          // 0..15
    const int ti  = tid & 15;          // 0..15

    for (int i = tid; i < KK; i += 256) nes[i] = ne[i];

    float xcol[8];
    #pragma unroll
    for (int j = 0; j < 8; ++j) xcol[j] = xn[b * TT + t0 + ti * 8 + j];

    float bestv[8];
    int   bestk[8];
    #pragma unroll
    for (int j = 0; j < 8; ++j) { bestv[j] = 3.4e38f; bestk[j] = 0; }

    const float* xbase = x + (size_t)b * DD * TT + t0;

    for (int kc = 0; kc < KK / BM; ++kc) {
        float acc[8][8];
        #pragma unroll
        for (int i = 0; i < 8; ++i)
            #pragma unroll
            for (int j = 0; j < 8; ++j) acc[i][j] = 0.f;

        for (int dc = 0; dc < DD / BKD; ++dc) {
            __syncthreads();   // protect LDS from previous iteration's readers
            // stage E^T chunk: 128 k-rows x 32 d  -> eT[d][k]
            {
                const int r0 = tid >> 3;      // 0..31
                const int c4 = tid & 7;       // d4 0..7
                #pragma unroll
                for (int p = 0; p < 4; ++p) {
                    const int r = r0 + p * 32;   // k-local 0..127
                    const float4 v = *reinterpret_cast<const float4*>(
                        emb + (size_t)(kc * BM + r) * DD + dc * BKD + c4 * 4);
                    eT[c4 * 4 + 0][r] = v.x;
                    eT[c4 * 4 + 1][r] = v.y;
                    eT[c4 * 4 + 2][r] = v.z;
                    eT[c4 * 4 + 3][r] = v.w;
                }
            }
            // stage X chunk: 32 d-rows x 128 t -> xs[d][t]
            {
                const int r0 = tid >> 5;      // 0..7
                const int c4 = tid & 31;      // t4 0..31
                #pragma unroll
                for (int p = 0; p < 4; ++p) {
                    const int r = r0 + p * 8;    // d-local 0..31
                    const float4 v = *reinterpret_cast<const float4*>(
                        xbase + (size_t)(dc * BKD + r) * TT + c4 * 4);
                    *reinterpret_cast<float4*>(&xs[r][c4 * 4]) = v;
                }
            }
            __syncthreads();

            #pragma unroll 8
            for (int d = 0; d < BKD; ++d) {
                float a[8], bb[8];
                *reinterpret_cast<float4*>(&a[0])  = *reinterpret_cast<const float4*>(&eT[d][ki * 8]);
                *reinterpret_cast<float4*>(&a[4])  = *reinterpret_cast<const float4*>(&eT[d][ki * 8 + 4]);
                *reinterpret_cast<float4*>(&bb[0]) = *reinterpret_cast<const float4*>(&xs[d][ti * 8]);
                *reinterpret_cast<float4*>(&bb[4]) = *reinterpret_cast<const float4*>(&xs[d][ti * 8 + 4]);
                #pragma unroll
                for (int i = 0; i < 8; ++i)
                    #pragma unroll
                    for (int j = 0; j < 8; ++j)
                        acc[i][j] = fmaf(a[i], bb[j], acc[i][j]);
            }
        }
        // fold this kc's scores into the running argmin, replicating numpy's
        // fp32 rounding: dist = fl( fl(xnorm + enorm) - fl(2*dot) )
        #pragma unroll
        for (int i = 0; i < 8; ++i) {
            const int k = kc * BM + ki * 8 + i;
            const float nv = nes[k];
            #pragma unroll
            for (int j = 0; j < 8; ++j) {
                const float t1    = __fadd_rn(xcol[j], nv);
                const float score = __fsub_rn(t1, __fmul_rn(2.0f, acc[i][j]));
                if (score < bestv[j] || (score == bestv[j] && k < bestk[j])) {
                    bestv[j] = score; bestk[j] = k;
                }
            }
        }
    }

    // cross-thread (over ki) argmin per t-column
    __syncthreads();
    #pragma unroll
    for (int j = 0; j < 8; ++j) { redv[ki][ti][j] = bestv[j]; redi[ki][ti][j] = bestk[j]; }
    __syncthreads();
    if (tid < 128) {
        const int tti = tid >> 3, j = tid & 7;
        float bv = redv[0][tti][j];
        int   bk = redi[0][tti][j];
        #pragma unroll
        for (int q = 1; q < 16; ++q) {
            const float v = redv[q][tti][j];
            const int  k2 = redi[q][tti][j];
            if (v < bv || (v == bv && k2 < bk)) { bv = v; bk = k2; }
        }
        const int t = t0 + tti * 8 + j;
        out_idx[b * TT + t] = bk;
    }
}

// ---------------- kernel C: gather + q_out + loss partials + counts ----------------
__global__ __launch_bounds__(256) void vq_gather(
    const float* __restrict__ x, const float* __restrict__ emb,
    const int* __restrict__ idx, float* __restrict__ out,
    int* __restrict__ counts, double* __restrict__ loss_acc)
{
    const int n = blockIdx.x * 256 + threadIdx.x;   // grid = N/256
    const int b = n >> 12;
    const int t = n & 4095;
    const int id = idx[n];
    const float* erow = emb + (size_t)id * DD;
    const float* xcol = x   + (size_t)b * DD * TT + t;
    float* ocol       = out + (size_t)b * DD * TT + t;

    float s = 0.f;
    #pragma unroll 4
    for (int d4 = 0; d4 < DD / 4; ++d4) {
        const float4 ev = *reinterpret_cast<const float4*>(erow + d4 * 4);
        const float e0 = ev.x, e1 = ev.y, e2 = ev.z, e3 = ev.w;
        const size_t base = (size_t)(d4 * 4) * TT;
        float xv, df;
        xv = xcol[base];            ocol[base]            = e0; df = e0 - xv; s = fmaf(df, df, s);
        xv = xcol[base + TT];       ocol[base + TT]       = e1; df = e1 - xv; s = fmaf(df, df, s);
        xv = xcol[base + 2 * TT];   ocol[base + 2 * TT]   = e2; df = e2 - xv; s = fmaf(df, df, s);
        xv = xcol[base + 3 * TT];   ocol[base + 3 * TT]   = e3; df = e3 - xv; s = fmaf(df, df, s);
    }
    out[IDX_OFF + n] = (float)id;
    atomicAdd(&counts[id], 1);

    __shared__ double red[256];
    red[threadIdx.x] = (double)s;
    __syncthreads();
    for (int off = 128; off; off >>= 1) {
        if (threadIdx.x < off) red[threadIdx.x] += red[threadIdx.x + off];
        __syncthreads();
    }
    if (threadIdx.x == 0) atomicAdd(loss_acc, red[0]);
}

// ---------------- kernel D: scalars ----------------
__global__ void vq_finalize(const int* __restrict__ counts,
                            const double* __restrict__ loss_acc,
                            float* __restrict__ out)
{
    __shared__ double red[256];
    const int tid = threadIdx.x;
    double s = 0.0;
    for (int k = tid; k < KK; k += 256) {
        const double p = (double)counts[k] / (double)NN;
        s += p * log(p + 1e-10);
    }
    red[tid] = s;
    __syncthreads();
    for (int off = 128; off; off >>= 1) {
        if (tid < off) red[tid] += red[tid + off];
        __syncthreads();
    }
    if (tid == 0) {
        out[PERP_POS] = (float)exp(-red[0]);
        out[LOSS_POS] = (float)(1.25 * loss_acc[0] / (double)QSZ);
    }
}

extern "C" void kernel_launch(void* const* d_in, const int* in_sizes, int n_in,
                              void* d_out, int out_size, void* d_ws, size_t ws_size,
                              hipStream_t stream) {
    const float* x   = (const float*)d_in[0];   // [16,256,4096]
    const float* emb = (const float*)d_in[1];   // [1024,256]
    float* out = (float*)d_out;
    char*  ws  = (char*)d_ws;

    float*  ne       = (float*)(ws + WS_NE);
    int*    idx      = (int*)(ws + WS_IDX);
    int*    counts   = (int*)(ws + WS_CNT);
    double* loss_acc = (double*)(ws + WS_LOSS);
    float*  xn       = (float*)(ws + WS_XN);

    hipMemsetAsync(ws + WS_CNT, 0, KK * 4 + 8, stream);   // counts + loss accumulator

    vq_knorm<<<KK / 256, 256, 0, stream>>>(emb, ne);
    vq_xnorm<<<NN / 256, 256, 0, stream>>>(x, xn);
    vq_argmin<<<BB * (TT / BN), 256, 0, stream>>>(x, emb, ne, xn, idx);
    vq_gather<<<NN / 256, 256, 0, stream>>>(x, emb, idx, out, counts, loss_acc);
    vq_finalize<<<1, 256, 0, stream>>>(counts, loss_acc, out);
}

// Round 3
// 538.680 us; speedup vs baseline: 1.1299x; 1.1299x over previous
//
#include <hip/hip_runtime.h>
#include <math.h>

#define DD 256
#define KK 1024
#define TT 4096
#define BB 16
#define NN (BB*TT)            // 65536
#define QSZ (BB*DD*TT)        // 16777216
#define LOSS_POS QSZ
#define IDX_OFF (QSZ+1)
#define PERP_POS (QSZ+1+NN)

// workspace layout (bytes)
#define WS_NE    0            // K f32
#define WS_XN    4096         // N f32
#define WS_IDX   266240       // N int
#define WS_CNT   528384       // K int   (zeroed)
#define WS_LOSS  532480       // double  (zeroed)
#define WS_FLAG  532488       // int + pad (zeroed)
#define WS_LIST  532496       // N int

#define THR 4e-4f             // flag threshold: ulp(512) + 2*B with big margin

typedef __attribute__((ext_vector_type(8))) short short8v;
typedef __attribute__((ext_vector_type(4))) float f32x4;

__device__ __forceinline__ unsigned short f2bf(float f) {   // fp32 -> bf16 RNE
    unsigned b = __float_as_uint(f);
    return (unsigned short)((b + 0x7FFFu + ((b >> 16) & 1u)) >> 16);
}
__device__ __forceinline__ unsigned mapf(float f) {         // order-preserving f32->u32
    unsigned b = __float_as_uint(f);
    return (b & 0x80000000u) ? ~b : (b | 0x80000000u);
}

// ---- numpy-exact pairwise sum of squares over 256 elements ----
__device__ __forceinline__ float np_pairwise_sq(const float* __restrict__ p,
                                                const long stride) {
    float tot[2];
    #pragma unroll
    for (int h = 0; h < 2; ++h) {
        const float* q = p + (long)h * 128 * stride;
        float r[8];
        #pragma unroll
        for (int j = 0; j < 8; ++j) {
            const float v = q[(long)j * stride];
            r[j] = __fmul_rn(v, v);
        }
        for (int i = 8; i < 128; i += 8) {
            #pragma unroll
            for (int j = 0; j < 8; ++j) {
                const float v = q[(long)(i + j) * stride];
                r[j] = __fadd_rn(r[j], __fmul_rn(v, v));
            }
        }
        tot[h] = __fadd_rn(__fadd_rn(__fadd_rn(r[0], r[1]), __fadd_rn(r[2], r[3])),
                           __fadd_rn(__fadd_rn(r[4], r[5]), __fadd_rn(r[6], r[7])));
    }
    return __fadd_rn(tot[0], tot[1]);
}

__global__ __launch_bounds__(256) void vq_knorm(const float* __restrict__ emb,
                                                float* __restrict__ ne) {
    const int k = blockIdx.x * 256 + threadIdx.x;
    if (k < KK) ne[k] = np_pairwise_sq(emb + (size_t)k * DD, 1);
}

__global__ __launch_bounds__(256) void vq_xnorm(const float* __restrict__ x,
                                                float* __restrict__ xn) {
    const int n = blockIdx.x * 256 + threadIdx.x;
    const int b = n >> 12;
    const int t = n & 4095;
    xn[n] = np_pairwise_sq(x + (size_t)b * DD * TT + t, TT);
}

// ---------------- main: bf16-MFMA approx scores + top-2 fold + flag ----------------
// block: 256 thr (4 waves), t-tile 128 (32/wave), k-chunks of 128, d-chunks of 32
#define ELDP 40   // padded LDS stride in bf16 (80 B rows, 16B-aligned, non-pow2 banks)

__global__ __launch_bounds__(256) void vq_argmin_mfma(
    const float* __restrict__ x,    // [B, D, T]
    const float* __restrict__ emb,  // [K, D] fp32
    const float* __restrict__ ne,   // [K]
    const float* __restrict__ xn,   // [N]
    int* __restrict__ out_idx,      // [N]
    int* __restrict__ flag_cnt,
    int* __restrict__ flag_list)
{
    __shared__ unsigned short Elds[2][128 * ELDP];  // 2 x 10 KiB
    __shared__ float nes[KK];                        // 4 KiB

    const int tid = threadIdx.x;
    const int w   = tid >> 6;        // wave 0..3
    const int l   = tid & 63;
    const int l15 = l & 15;
    const int lg  = l >> 4;          // 0..3
    const int bx  = blockIdx.x;      // 512
    const int b   = bx >> 5;
    const int t0  = (bx & 31) * 128;
    const int tw0 = t0 + w * 32;

    for (int i = tid; i < KK; i += 256) nes[i] = ne[i];

    // X fragments -> registers (bf16), loaded once. lane: t = tw0+ft*16+l15,
    // d = dc*32 + lg*8 + j  (B-operand layout of mfma_f32_16x16x32_bf16)
    short8v Bf[2][8];
    const float* xb = x + (size_t)b * DD * TT;
    #pragma unroll
    for (int ft = 0; ft < 2; ++ft) {
        const int t = tw0 + ft * 16 + l15;
        #pragma unroll
        for (int dc = 0; dc < 8; ++dc) {
            const int d0 = dc * 32 + lg * 8;
            short8v v;
            #pragma unroll
            for (int j = 0; j < 8; ++j)
                v[j] = (short)f2bf(xb[(size_t)(d0 + j) * TT + t]);
            Bf[ft][dc] = v;
        }
    }
    float xnv[2];
    xnv[0] = xn[b * TT + tw0 + l15];
    xnv[1] = xn[b * TT + tw0 + 16 + l15];

    float v1[2] = {3.4028235e38f, 3.4028235e38f};
    float v2[2] = {3.4028235e38f, 3.4028235e38f};
    int   k1[2] = {0, 0};

    // staging assignment: thread -> row srow (0..127), col half sh (16 floats)
    const int srow = tid >> 1, sh = tid & 1;

    f32x4 acc[8][2];
    float sreg[16];

    // prologue: stage step 0 (kc=0, dc=0)
    {
        const float* src = emb + (size_t)srow * DD + sh * 16;
        #pragma unroll
        for (int q = 0; q < 4; ++q) {
            const float4 v = *reinterpret_cast<const float4*>(src + q * 4);
            sreg[q * 4 + 0] = v.x; sreg[q * 4 + 1] = v.y;
            sreg[q * 4 + 2] = v.z; sreg[q * 4 + 3] = v.w;
        }
        unsigned short u[16];
        #pragma unroll
        for (int q = 0; q < 16; ++q) u[q] = f2bf(sreg[q]);
        short8v w0, w1;
        #pragma unroll
        for (int q = 0; q < 8; ++q) { w0[q] = (short)u[q]; w1[q] = (short)u[q + 8]; }
        *reinterpret_cast<short8v*>(&Elds[0][srow * ELDP + sh * 16])     = w0;
        *reinterpret_cast<short8v*>(&Elds[0][srow * ELDP + sh * 16 + 8]) = w1;
    }
    __syncthreads();

    for (int s = 0; s < 64; ++s) {
        const int kc = s >> 3, dc = s & 7;

        if (dc == 0) {
            const f32x4 z = {0.f, 0.f, 0.f, 0.f};
            #pragma unroll
            for (int fk = 0; fk < 8; ++fk)
                #pragma unroll
                for (int ft = 0; ft < 2; ++ft) acc[fk][ft] = z;
        }

        // issue global loads for next step
        if (s + 1 < 64) {
            const int kn = (s + 1) >> 3, dn = (s + 1) & 7;
            const float* src = emb + (size_t)(kn * 128 + srow) * DD + dn * 32 + sh * 16;
            #pragma unroll
            for (int q = 0; q < 4; ++q) {
                const float4 v = *reinterpret_cast<const float4*>(src + q * 4);
                sreg[q * 4 + 0] = v.x; sreg[q * 4 + 1] = v.y;
                sreg[q * 4 + 2] = v.z; sreg[q * 4 + 3] = v.w;
            }
        }

        // MFMA on current buffer
        {
            const unsigned short* eb = &Elds[s & 1][0];
            short8v Af[8];
            #pragma unroll
            for (int fk = 0; fk < 8; ++fk)
                Af[fk] = *reinterpret_cast<const short8v*>(
                    &eb[(fk * 16 + l15) * ELDP + lg * 8]);
            #pragma unroll
            for (int fk = 0; fk < 8; ++fk)
                #pragma unroll
                for (int ft = 0; ft < 2; ++ft)
                    acc[fk][ft] = __builtin_amdgcn_mfma_f32_16x16x32_bf16(
                        Af[fk], Bf[ft][dc], acc[fk][ft], 0, 0, 0);
        }

        // fold at end of each k-chunk
        if (dc == 7) {
            #pragma unroll
            for (int ft = 0; ft < 2; ++ft) {
                #pragma unroll
                for (int fk = 0; fk < 8; ++fk) {
                    const float4 nev = *reinterpret_cast<const float4*>(
                        &nes[kc * 128 + fk * 16 + lg * 4]);
                    const float nv[4] = {nev.x, nev.y, nev.z, nev.w};
                    #pragma unroll
                    for (int r = 0; r < 4; ++r) {
                        const float sc = fmaf(-2.0f, acc[fk][ft][r], xnv[ft] + nv[r]);
                        const float mx = fmaxf(v1[ft], sc);
                        v2[ft] = fminf(v2[ft], mx);
                        const bool c = sc < v1[ft];
                        v1[ft] = c ? sc : v1[ft];
                        k1[ft] = c ? (kc * 128 + fk * 16 + lg * 4 + r) : k1[ft];
                    }
                }
            }
        }

        __syncthreads();
        if (s + 1 < 64) {
            unsigned short u[16];
            #pragma unroll
            for (int q = 0; q < 16; ++q) u[q] = f2bf(sreg[q]);
            short8v w0, w1;
            #pragma unroll
            for (int q = 0; q < 8; ++q) { w0[q] = (short)u[q]; w1[q] = (short)u[q + 8]; }
            unsigned short* ebn = &Elds[(s + 1) & 1][0];
            *reinterpret_cast<short8v*>(&ebn[srow * ELDP + sh * 16])     = w0;
            *reinterpret_cast<short8v*>(&ebn[srow * ELDP + sh * 16 + 8]) = w1;
        }
        __syncthreads();
    }

    // cross-lane merge over lg groups (k-partition), then write
    #pragma unroll
    for (int ft = 0; ft < 2; ++ft) {
        #pragma unroll
        for (int m = 16; m <= 32; m <<= 1) {
            const float ov1 = __shfl_xor(v1[ft], m);
            const float ov2 = __shfl_xor(v2[ft], m);
            const int   ok1 = __shfl_xor(k1[ft], m);
            const float mx  = fmaxf(v1[ft], ov1);
            v2[ft] = fminf(fminf(v2[ft], ov2), mx);
            const bool take = (ov1 < v1[ft]) || (ov1 == v1[ft] && ok1 < k1[ft]);
            v1[ft] = take ? ov1 : v1[ft];
            k1[ft] = take ? ok1 : k1[ft];
        }
        if (l < 16) {
            const int t = tw0 + ft * 16 + l15;
            const int n = b * TT + t;
            out_idx[n] = k1[ft];
            if (v2[ft] - v1[ft] <= THR) {
                const int p = atomicAdd(flag_cnt, 1);
                flag_list[p] = n;
            }
        }
    }
}

// ---------------- cleanup: exact fp32 rescore of flagged rows ----------------
#define CROWS 4
__global__ __launch_bounds__(256) void vq_cleanup(
    const float* __restrict__ x, const float* __restrict__ emb,
    const float* __restrict__ ne, const float* __restrict__ xn,
    const int* __restrict__ flag_cnt, const int* __restrict__ flag_list,
    int* __restrict__ out_idx)
{
    __shared__ float xr[CROWS][DD];
    __shared__ float xns[CROWS];
    __shared__ int   rowid[CROWS];
    __shared__ unsigned long long red[256];

    const int tid = threadIdx.x;
    const int cnt = *flag_cnt;

    for (int base = blockIdx.x * CROWS; base < cnt; base += gridDim.x * CROWS) {
        const int nr = min(CROWS, cnt - base);
        if (tid < CROWS) {
            const int n = flag_list[base + ((tid < nr) ? tid : 0)];
            rowid[tid] = n;
            xns[tid]   = xn[n];
        }
        __syncthreads();
        for (int j = 0; j < CROWS; ++j) {
            const int n = rowid[j], bb = n >> 12, t = n & 4095;
            xr[j][tid] = x[(size_t)bb * DD * TT + (size_t)tid * TT + t];
        }
        __syncthreads();

        unsigned long long best[CROWS];
        #pragma unroll
        for (int j = 0; j < CROWS; ++j) best[j] = ~0ull;

        for (int kk = 0; kk < 4; ++kk) {
            const int k = tid * 4 + kk;
            const float* er = emb + (size_t)k * DD;
            float dot[CROWS] = {0.f, 0.f, 0.f, 0.f};
            for (int d4 = 0; d4 < DD / 4; ++d4) {
                const float4 ev = *reinterpret_cast<const float4*>(er + d4 * 4);
                const float e[4] = {ev.x, ev.y, ev.z, ev.w};
                #pragma unroll
                for (int q = 0; q < 4; ++q)
                    #pragma unroll
                    for (int j = 0; j < CROWS; ++j)
                        dot[j] = fmaf(e[q], xr[j][d4 * 4 + q], dot[j]);
            }
            const float nv = ne[k];
            #pragma unroll
            for (int j = 0; j < CROWS; ++j) {
                const float s1 = __fadd_rn(xns[j], nv);
                const float sc = __fsub_rn(s1, __fmul_rn(2.0f, dot[j]));
                const unsigned long long pk =
                    ((unsigned long long)mapf(sc) << 32) | (unsigned)k;
                best[j] = (pk < best[j]) ? pk : best[j];
            }
        }

        for (int j = 0; j < CROWS; ++j) {
            red[tid] = best[j];
            __syncthreads();
            for (int off = 128; off; off >>= 1) {
                if (tid < off) red[tid] = (red[tid + off] < red[tid]) ? red[tid + off] : red[tid];
                __syncthreads();
            }
            if (tid == 0 && j < nr)
                out_idx[rowid[j]] = (int)(red[0] & 0xFFFFFFFFu);
            __syncthreads();
        }
        __syncthreads();
    }
}

// ---------------- gather + q_out + loss partials + counts ----------------
__global__ __launch_bounds__(256) void vq_gather(
    const float* __restrict__ x, const float* __restrict__ emb,
    const int* __restrict__ idx, float* __restrict__ out,
    int* __restrict__ counts, double* __restrict__ loss_acc)
{
    const int n = blockIdx.x * 256 + threadIdx.x;
    const int b = n >> 12;
    const int t = n & 4095;
    const int id = idx[n];
    const float* erow = emb + (size_t)id * DD;
    const float* xcol = x   + (size_t)b * DD * TT + t;
    float* ocol       = out + (size_t)b * DD * TT + t;

    float s = 0.f;
    #pragma unroll 4
    for (int d4 = 0; d4 < DD / 4; ++d4) {
        const float4 ev = *reinterpret_cast<const float4*>(erow + d4 * 4);
        const float e0 = ev.x, e1 = ev.y, e2 = ev.z, e3 = ev.w;
        const size_t base = (size_t)(d4 * 4) * TT;
        float xv, df;
        xv = xcol[base];            ocol[base]            = e0; df = e0 - xv; s = fmaf(df, df, s);
        xv = xcol[base + TT];       ocol[base + TT]       = e1; df = e1 - xv; s = fmaf(df, df, s);
        xv = xcol[base + 2 * TT];   ocol[base + 2 * TT]   = e2; df = e2 - xv; s = fmaf(df, df, s);
        xv = xcol[base + 3 * TT];   ocol[base + 3 * TT]   = e3; df = e3 - xv; s = fmaf(df, df, s);
    }
    out[IDX_OFF + n] = (float)id;
    atomicAdd(&counts[id], 1);

    __shared__ double red[256];
    red[threadIdx.x] = (double)s;
    __syncthreads();
    for (int off = 128; off; off >>= 1) {
        if (threadIdx.x < off) red[threadIdx.x] += red[threadIdx.x + off];
        __syncthreads();
    }
    if (threadIdx.x == 0) atomicAdd(loss_acc, red[0]);
}

__global__ void vq_finalize(const int* __restrict__ counts,
                            const double* __restrict__ loss_acc,
                            float* __restrict__ out)
{
    __shared__ double red[256];
    const int tid = threadIdx.x;
    double s = 0.0;
    for (int k = tid; k < KK; k += 256) {
        const double p = (double)counts[k] / (double)NN;
        s += p * log(p + 1e-10);
    }
    red[tid] = s;
    __syncthreads();
    for (int off = 128; off; off >>= 1) {
        if (tid < off) red[tid] += red[tid + off];
        __syncthreads();
    }
    if (tid == 0) {
        out[PERP_POS] = (float)exp(-red[0]);
        out[LOSS_POS] = (float)(1.25 * loss_acc[0] / (double)QSZ);
    }
}

extern "C" void kernel_launch(void* const* d_in, const int* in_sizes, int n_in,
                              void* d_out, int out_size, void* d_ws, size_t ws_size,
                              hipStream_t stream) {
    const float* x   = (const float*)d_in[0];   // [16,256,4096]
    const float* emb = (const float*)d_in[1];   // [1024,256]
    float* out = (float*)d_out;
    char*  ws  = (char*)d_ws;

    float*  ne        = (float*)(ws + WS_NE);
    float*  xn        = (float*)(ws + WS_XN);
    int*    idx       = (int*)(ws + WS_IDX);
    int*    counts    = (int*)(ws + WS_CNT);
    double* loss_acc  = (double*)(ws + WS_LOSS);
    int*    flag_cnt  = (int*)(ws + WS_FLAG);
    int*    flag_list = (int*)(ws + WS_LIST);

    hipMemsetAsync(ws + WS_CNT, 0, 4096 + 16, stream);  // counts + loss + flagcnt

    vq_knorm<<<KK / 256, 256, 0, stream>>>(emb, ne);
    vq_xnorm<<<NN / 256, 256, 0, stream>>>(x, xn);
    vq_argmin_mfma<<<512, 256, 0, stream>>>(x, emb, ne, xn, idx, flag_cnt, flag_list);
    vq_cleanup<<<256, 256, 0, stream>>>(x, emb, ne, xn, flag_cnt, flag_list, idx);
    vq_gather<<<NN / 256, 256, 0, stream>>>(x, emb, idx, out, counts, loss_acc);
    vq_finalize<<<1, 256, 0, stream>>>(counts, loss_acc, out);
}

// Round 4
// 425.445 us; speedup vs baseline: 1.4306x; 1.2662x over previous
//
#include <hip/hip_runtime.h>
#include <math.h>

#define DD 256
#define KK 1024
#define TT 4096
#define BB 16
#define NN (BB*TT)            // 65536
#define QSZ (BB*DD*TT)        // 16777216
#define LOSS_POS QSZ
#define IDX_OFF (QSZ+1)
#define PERP_POS (QSZ+1+NN)

// ws layout (proven footprint < 532 KB)
#define WS_NE    0                   // K f32
#define WS_IDX   4096                // N int
#define WS_CNT   (4096 + NN*4)       // K int    (zeroed)
#define WS_LOSS  (WS_CNT + KK*4)     // double   (zeroed)
#define WS_FLAG  (WS_LOSS + 8)       // int      (zeroed)

// scratch carved out of the q_out region (only clobbered by the final gather)
#define OUT_EH   0                   // K*D fp16 (512 KB)
#define OUT_XN   (1u<<20)            // N f32    (256 KB)
#define OUT_FL   (2u<<20)            // N int    (256 KB)

#define THR 1.4e-4f                  // fp32-grid (3.05e-5) + 2*(7.5 sigma fp16 err + fold ulp)

typedef __attribute__((ext_vector_type(8))) _Float16 half8v;
typedef __attribute__((ext_vector_type(4))) float f32x4;

__device__ __forceinline__ unsigned mapf(float f) {   // order-preserving f32->u32
    unsigned b = __float_as_uint(f);
    return (b & 0x80000000u) ? ~b : (b | 0x80000000u);
}

// ---- numpy-exact pairwise sum of squares over 256 elements ----
__device__ __forceinline__ float np_pairwise_sq(const float* __restrict__ p,
                                                const long stride) {
    float tot[2];
    #pragma unroll
    for (int h = 0; h < 2; ++h) {
        const float* q = p + (long)h * 128 * stride;
        float r[8];
        #pragma unroll
        for (int j = 0; j < 8; ++j) {
            const float v = q[(long)j * stride];
            r[j] = __fmul_rn(v, v);
        }
        for (int i = 8; i < 128; i += 8) {
            #pragma unroll
            for (int j = 0; j < 8; ++j) {
                const float v = q[(long)(i + j) * stride];
                r[j] = __fadd_rn(r[j], __fmul_rn(v, v));
            }
        }
        tot[h] = __fadd_rn(__fadd_rn(__fadd_rn(r[0], r[1]), __fadd_rn(r[2], r[3])),
                           __fadd_rn(__fadd_rn(r[4], r[5]), __fadd_rn(r[6], r[7])));
    }
    return __fadd_rn(tot[0], tot[1]);
}

// ---------------- prep: ||e_k||^2 (np-exact) + eh = fp16(1024*e) ----------------
__global__ __launch_bounds__(256) void vq_prep_e(const float* __restrict__ emb,
                                                 float* __restrict__ ne,
                                                 _Float16* __restrict__ eh) {
    const int k = blockIdx.x * 256 + threadIdx.x;   // grid = KK/256
    const float* row = emb + (size_t)k * DD;
    ne[k] = np_pairwise_sq(row, 1);
    _Float16* er = eh + (size_t)k * DD;
    #pragma unroll 8
    for (int d = 0; d < DD; ++d) er[d] = (_Float16)(row[d] * 1024.0f);
}

// ---------------- ||x_n||^2 (np-exact) ----------------
__global__ __launch_bounds__(256) void vq_xnorm(const float* __restrict__ x,
                                                float* __restrict__ xn) {
    const int n = blockIdx.x * 256 + threadIdx.x;   // grid = NN/256
    const int b = n >> 12;
    const int t = n & 4095;
    xn[n] = np_pairwise_sq(x + (size_t)b * DD * TT + t, TT);
}

// ---------------- main: fp16-MFMA scores + top-2 fold + flag ----------------
// 4 waves, per-wave t-tile 32 (2 frags), k-chunks 128, d-chunks 32, dbuf LDS E
__global__ __launch_bounds__(256) void vq_argmin_f16(
    const float* __restrict__ x,       // [B, D, T] fp32
    const _Float16* __restrict__ eh,   // [K, D] fp16 (x1024)
    const float* __restrict__ ne,      // [K]
    const float* __restrict__ xn,      // [N]
    int* __restrict__ out_idx,
    int* __restrict__ flag_cnt,
    int* __restrict__ flag_list)
{
    __shared__ __align__(16) _Float16 Elds[2][128 * 32];  // 2 x 8 KB
    __shared__ float nes[KK];                             // 4 KB

    const int tid = threadIdx.x;
    const int w   = tid >> 6;
    const int l   = tid & 63;
    const int l15 = l & 15;
    const int lg  = l >> 4;
    const int bx  = blockIdx.x;        // 512
    const int b   = bx >> 5;
    const int t0  = (bx & 31) * 128;
    const int tw0 = t0 + w * 32;

    for (int i = tid; i < KK; i += 256) nes[i] = ne[i];

    // B fragments: x -> fp16 registers (layout proven in round 3)
    half8v Bf[2][8];
    const float* xb = x + (size_t)b * DD * TT;
    #pragma unroll
    for (int ft = 0; ft < 2; ++ft) {
        const int t = tw0 + ft * 16 + l15;
        #pragma unroll
        for (int dc = 0; dc < 8; ++dc) {
            const int d0 = dc * 32 + lg * 8;
            half8v v;
            #pragma unroll
            for (int j = 0; j < 8; ++j) v[j] = (_Float16)xb[(size_t)(d0 + j) * TT + t];
            Bf[ft][dc] = v;
        }
    }
    const float xnv[2] = { xn[b * TT + tw0 + l15], xn[b * TT + tw0 + 16 + l15] };

    float v1[2] = {3.4028235e38f, 3.4028235e38f};
    float v2[2] = {3.4028235e38f, 3.4028235e38f};
    int   k1[2] = {0, 0};

    // staging: thread covers slots tid and tid+256 of 512 (128 rows x 4 chunks)
    const int row0 = tid >> 2;          // 0..63
    const int row1 = row0 + 64;         // 64..127
    const int cg   = tid & 3;
    const int xc0  = cg ^ ((row0 >> 1) & 3);   // source-chunk swizzle
    const int xc1  = cg ^ ((row1 >> 1) & 3);

    half8v g0, g1;
    // prologue: stage step 0 (kc=0, dc=0)
    g0 = *(const half8v*)(eh + (size_t)row0 * DD + xc0 * 8);
    g1 = *(const half8v*)(eh + (size_t)row1 * DD + xc1 * 8);
    *(half8v*)&Elds[0][row0 * 32 + cg * 8] = g0;
    *(half8v*)&Elds[0][row1 * 32 + cg * 8] = g1;
    __syncthreads();

    f32x4 acc[8][2];
    const int rsw = (lg ^ ((l15 >> 1) & 3)) * 8;   // read-side swizzle (halves)

    for (int s = 0; s < 64; ++s) {
        const int kc = s >> 3, dc = s & 7;

        if (dc == 0) {
            #pragma unroll
            for (int fk = 0; fk < 8; ++fk) {
                acc[fk][0] = f32x4{0.f, 0.f, 0.f, 0.f};
                acc[fk][1] = f32x4{0.f, 0.f, 0.f, 0.f};
            }
        }

        if (s + 1 < 64) {
            const int kn = (s + 1) >> 3, dn = (s + 1) & 7;
            g0 = *(const half8v*)(eh + (size_t)(kn * 128 + row0) * DD + dn * 32 + xc0 * 8);
            g1 = *(const half8v*)(eh + (size_t)(kn * 128 + row1) * DD + dn * 32 + xc1 * 8);
        }

        {
            const _Float16* eb = Elds[s & 1];
            #pragma unroll
            for (int fk = 0; fk < 8; ++fk) {
                const half8v Af = *(const half8v*)&eb[(fk * 16 + l15) * 32 + rsw];
                acc[fk][0] = __builtin_amdgcn_mfma_f32_16x16x32_f16(Af, Bf[0][dc], acc[fk][0], 0, 0, 0);
                acc[fk][1] = __builtin_amdgcn_mfma_f32_16x16x32_f16(Af, Bf[1][dc], acc[fk][1], 0, 0, 0);
            }
        }

        if (dc == 7) {
            #pragma unroll
            for (int ft = 0; ft < 2; ++ft) {
                #pragma unroll
                for (int fk = 0; fk < 8; ++fk) {
                    const float4 nev = *reinterpret_cast<const float4*>(
                        &nes[kc * 128 + fk * 16 + lg * 4]);
                    const float nv[4] = {nev.x, nev.y, nev.z, nev.w};
                    #pragma unroll
                    for (int r = 0; r < 4; ++r) {
                        const float sa = __fadd_rn(xnv[ft], nv[r]);
                        // dot' = 1024*dot  ->  score = sa - 2^-9 * dot'
                        const float sc = fmaf(-0.001953125f, acc[fk][ft][r], sa);
                        const float mx = fmaxf(v1[ft], sc);
                        v2[ft] = fminf(v2[ft], mx);
                        const bool c = sc < v1[ft];
                        v1[ft] = c ? sc : v1[ft];
                        k1[ft] = c ? (kc * 128 + fk * 16 + lg * 4 + r) : k1[ft];
                    }
                }
            }
        }

        __syncthreads();
        if (s + 1 < 64) {
            _Float16* ebn = Elds[(s + 1) & 1];
            *(half8v*)&ebn[row0 * 32 + cg * 8] = g0;
            *(half8v*)&ebn[row1 * 32 + cg * 8] = g1;
        }
        __syncthreads();
    }

    // cross-lane merge over lg groups (k-partition), then write + flag
    #pragma unroll
    for (int ft = 0; ft < 2; ++ft) {
        #pragma unroll
        for (int m = 16; m <= 32; m <<= 1) {
            const float ov1 = __shfl_xor(v1[ft], m);
            const float ov2 = __shfl_xor(v2[ft], m);
            const int   ok1 = __shfl_xor(k1[ft], m);
            const float mx  = fmaxf(v1[ft], ov1);
            v2[ft] = fminf(fminf(v2[ft], ov2), mx);
            const bool take = (ov1 < v1[ft]) || (ov1 == v1[ft] && ok1 < k1[ft]);
            v1[ft] = take ? ov1 : v1[ft];
            k1[ft] = take ? ok1 : k1[ft];
        }
        if (l < 16) {
            const int n = b * TT + tw0 + ft * 16 + l15;
            out_idx[n] = k1[ft];
            if (v2[ft] - v1[ft] <= THR) {
                const int p = atomicAdd(flag_cnt, 1);
                flag_list[p] = n;
            }
        }
    }
}

// ---------------- cleanup: exact fp32 rescore of flagged rows ----------------
#define CR 16
__global__ __launch_bounds__(512) void vq_cleanup(
    const float* __restrict__ x, const float* __restrict__ emb,
    const float* __restrict__ ne, const float* __restrict__ xn,
    const int* __restrict__ flag_cnt, const int* __restrict__ flag_list,
    int* __restrict__ out_idx)
{
    __shared__ float xr[CR][DD + 4];
    __shared__ float xns_s[CR];
    __shared__ int rowid[CR];
    __shared__ unsigned long long wred[8][8];

    const int tid = threadIdx.x;
    const int wv  = tid >> 6, l = tid & 63;
    const int kt  = tid & 255;     // k0 = kt*4
    const int rt  = tid >> 8;      // rows rt*8 .. rt*8+7
    const int cnt = *flag_cnt;

    for (int base = blockIdx.x * CR; base < cnt; base += gridDim.x * CR) {
        const int nr = min(CR, cnt - base);
        __syncthreads();
        if (tid < CR) {
            const int n = flag_list[base + ((tid < nr) ? tid : (nr - 1))];
            rowid[tid] = n;
            xns_s[tid] = xn[n];
        }
        __syncthreads();
        {
            const int r = tid >> 5, d0 = (tid & 31) * 8;
            const int n = rowid[r], bb2 = n >> 12, t = n & 4095;
            const float* xc = x + (size_t)bb2 * DD * TT + t;
            #pragma unroll
            for (int q = 0; q < 8; ++q) xr[r][d0 + q] = xc[(size_t)(d0 + q) * TT];
        }
        __syncthreads();

        const int k0 = kt * 4;
        float acc4[4][8];
        #pragma unroll
        for (int a = 0; a < 4; ++a)
            #pragma unroll
            for (int r = 0; r < 8; ++r) acc4[a][r] = 0.f;

        for (int ch = 0; ch < DD / 8; ++ch) {
            const int d0 = ch * 8;
            float xc8[8][8];
            #pragma unroll
            for (int r = 0; r < 8; ++r) {
                const float4 xa = *reinterpret_cast<const float4*>(&xr[rt * 8 + r][d0]);
                const float4 xbv = *reinterpret_cast<const float4*>(&xr[rt * 8 + r][d0 + 4]);
                xc8[r][0] = xa.x;  xc8[r][1] = xa.y;  xc8[r][2] = xa.z;  xc8[r][3] = xa.w;
                xc8[r][4] = xbv.x; xc8[r][5] = xbv.y; xc8[r][6] = xbv.z; xc8[r][7] = xbv.w;
            }
            #pragma unroll
            for (int a = 0; a < 4; ++a) {
                const float* er = emb + (size_t)(k0 + a) * DD + d0;
                const float4 ea = *reinterpret_cast<const float4*>(er);
                const float4 eb2 = *reinterpret_cast<const float4*>(er + 4);
                const float ev[8] = {ea.x, ea.y, ea.z, ea.w, eb2.x, eb2.y, eb2.z, eb2.w};
                #pragma unroll
                for (int q = 0; q < 8; ++q)
                    #pragma unroll
                    for (int r = 0; r < 8; ++r)
                        acc4[a][r] = fmaf(ev[q], xc8[r][q], acc4[a][r]);
            }
        }

        #pragma unroll
        for (int r = 0; r < 8; ++r) {
            const float xnv2 = xns_s[rt * 8 + r];
            unsigned long long bb3 = ~0ull;
            #pragma unroll
            for (int a = 0; a < 4; ++a) {
                const float s1 = __fadd_rn(xnv2, ne[k0 + a]);
                const float sc = __fsub_rn(s1, __fmul_rn(2.0f, acc4[a][r]));
                const unsigned long long pk =
                    ((unsigned long long)mapf(sc) << 32) | (unsigned)(k0 + a);
                bb3 = (pk < bb3) ? pk : bb3;
            }
            unsigned long long v = bb3;
            #pragma unroll
            for (int m = 1; m < 64; m <<= 1) {
                const unsigned long long o = __shfl_xor(v, m);
                v = (o < v) ? o : v;
            }
            if (l == 0) wred[wv][r] = v;
        }
        __syncthreads();
        if (wv == 0) {
            const int row = l >> 2, sw = l & 3;
            const int srcw = (row < 8) ? sw : (4 + sw);
            unsigned long long v = wred[srcw][row & 7];
            #pragma unroll
            for (int m = 1; m < 4; m <<= 1) {
                const unsigned long long o = __shfl_xor(v, m);
                v = (o < v) ? o : v;
            }
            if (sw == 0 && row < nr) out_idx[rowid[row]] = (int)(v & 0xFFFFFFFFu);
        }
    }
}

// ---------------- gather + q_out + loss partials + counts ----------------
__global__ __launch_bounds__(256) void vq_gather(
    const float* __restrict__ x, const float* __restrict__ emb,
    const int* __restrict__ idx, float* __restrict__ out,
    int* __restrict__ counts, double* __restrict__ loss_acc)
{
    const int n = blockIdx.x * 256 + threadIdx.x;
    const int b = n >> 12;
    const int t = n & 4095;
    const int id = idx[n];
    const float* erow = emb + (size_t)id * DD;
    const float* xcol = x   + (size_t)b * DD * TT + t;
    float* ocol       = out + (size_t)b * DD * TT + t;

    float s = 0.f;
    #pragma unroll 4
    for (int d4 = 0; d4 < DD / 4; ++d4) {
        const float4 ev = *reinterpret_cast<const float4*>(erow + d4 * 4);
        const float e0 = ev.x, e1 = ev.y, e2 = ev.z, e3 = ev.w;
        const size_t base = (size_t)(d4 * 4) * TT;
        float xv, df;
        xv = xcol[base];            ocol[base]            = e0; df = e0 - xv; s = fmaf(df, df, s);
        xv = xcol[base + TT];       ocol[base + TT]       = e1; df = e1 - xv; s = fmaf(df, df, s);
        xv = xcol[base + 2 * TT];   ocol[base + 2 * TT]   = e2; df = e2 - xv; s = fmaf(df, df, s);
        xv = xcol[base + 3 * TT];   ocol[base + 3 * TT]   = e3; df = e3 - xv; s = fmaf(df, df, s);
    }
    out[IDX_OFF + n] = (float)id;
    atomicAdd(&counts[id], 1);

    __shared__ double red[256];
    red[threadIdx.x] = (double)s;
    __syncthreads();
    for (int off = 128; off; off >>= 1) {
        if (threadIdx.x < off) red[threadIdx.x] += red[threadIdx.x + off];
        __syncthreads();
    }
    if (threadIdx.x == 0) atomicAdd(loss_acc, red[0]);
}

__global__ void vq_finalize(const int* __restrict__ counts,
                            const double* __restrict__ loss_acc,
                            float* __restrict__ out)
{
    __shared__ double red[256];
    const int tid = threadIdx.x;
    double s = 0.0;
    for (int k = tid; k < KK; k += 256) {
        const double p = (double)counts[k] / (double)NN;
        s += p * log(p + 1e-10);
    }
    red[tid] = s;
    __syncthreads();
    for (int off = 128; off; off >>= 1) {
        if (tid < off) red[tid] += red[tid + off];
        __syncthreads();
    }
    if (tid == 0) {
        out[PERP_POS] = (float)exp(-red[0]);
        out[LOSS_POS] = (float)(1.25 * loss_acc[0] / (double)QSZ);
    }
}

extern "C" void kernel_launch(void* const* d_in, const int* in_sizes, int n_in,
                              void* d_out, int out_size, void* d_ws, size_t ws_size,
                              hipStream_t stream) {
    const float* x   = (const float*)d_in[0];   // [16,256,4096]
    const float* emb = (const float*)d_in[1];   // [1024,256]
    float* out = (float*)d_out;
    char*  ws  = (char*)d_ws;

    float*     ne        = (float*)(ws + WS_NE);
    int*       idx       = (int*)(ws + WS_IDX);
    int*       counts    = (int*)(ws + WS_CNT);
    double*    loss_acc  = (double*)(ws + WS_LOSS);
    int*       flag_cnt  = (int*)(ws + WS_FLAG);
    _Float16*  eh        = (_Float16*)((char*)d_out + OUT_EH);
    float*     xn        = (float*)((char*)d_out + OUT_XN);
    int*       flag_list = (int*)((char*)d_out + OUT_FL);

    hipMemsetAsync(ws + WS_CNT, 0, KK * 4 + 16, stream);  // counts + loss + flag_cnt

    vq_prep_e<<<KK / 256, 256, 0, stream>>>(emb, ne, eh);
    vq_xnorm<<<NN / 256, 256, 0, stream>>>(x, xn);
    vq_argmin_f16<<<512, 256, 0, stream>>>(x, eh, ne, xn, idx, flag_cnt, flag_list);
    vq_cleanup<<<256, 512, 0, stream>>>(x, emb, ne, xn, flag_cnt, flag_list, idx);
    vq_gather<<<NN / 256, 256, 0, stream>>>(x, emb, idx, out, counts, loss_acc);
    vq_finalize<<<1, 256, 0, stream>>>(counts, loss_acc, out);
}